// Round 2
// baseline (202.090 us; speedup 1.0000x reference)
//
#include <hip/hip_runtime.h>

// Problem constants
constexpr int      FRAMES  = 128 * 1024;              // B*T = 131072
constexpr int      FRAME_F = 150;                     // floats per frame
constexpr unsigned NT      = (unsigned)FRAMES * 50u;  // 6,553,600 bone triples
// final = 0.1 * (sum_abs + 0.1*sum_sq) / (FRAMES*150)
constexpr float    SCALE   = 0.1f / ((float)FRAMES * (float)FRAME_F);

constexpr int      BLOCK   = 256;
constexpr int      NBLK    = 1600;                    // partials = 6.4 KB (fits proven ws)
constexpr int      TPT     = 8;                       // triples per chunk (96 B, 16-B aligned)
constexpr unsigned NCHUNK  = NT / TPT;                // 819,200 chunks
constexpr unsigned CSTRIDE = (unsigned)NBLK * BLOCK;  // 409,600 threads; 2 chunks/thread

// One bone term from raw (unmasked) self triple (p,t) and neighbor triple (q,u).
__device__ __forceinline__ float bone_term(
    float p0, float p1, float p2, float t0, float t1, float t2,
    float q0, float q1, float q2, float u0, float u1, float u2)
{
    // masks: targets*mask == targets identically; mask preds only
    const float m0 = (t0 != 0.0f) ? 1.0f : 0.0f;
    const float m1 = (t1 != 0.0f) ? 1.0f : 0.0f;
    const float m2 = (t2 != 0.0f) ? 1.0f : 0.0f;
    const float n0 = (u0 != 0.0f) ? 1.0f : 0.0f;
    const float n1 = (u1 != 0.0f) ? 1.0f : 0.0f;
    const float n2 = (u2 != 0.0f) ? 1.0f : 0.0f;

    const float pm0 = p0 * m0, pm1 = p1 * m1, pm2 = p2 * m2;
    const float qm0 = q0 * n0, qm1 = q1 * n1, qm2 = q2 * n2;

    // L1 term over this triple
    const float ab = fabsf(pm0 - t0) + fabsf(pm1 - t1) + fabsf(pm2 - t2);

    // bone direction term
    const float pd0 = pm0 - qm0, pd1 = pm1 - qm1, pd2 = pm2 - qm2;
    const float td0 = t0 - u0,   td1 = t1 - u1,   td2 = t2 - u2;

    const float pl2 = pd0*pd0 + pd1*pd1 + pd2*pd2;
    const float tl2 = td0*td0 + td1*td1 + td2*td2;
    const float pri = (pl2 > 0.0f) ? __builtin_amdgcn_rsqf(pl2) : 0.0f;
    const float tri = (tl2 > 0.0f) ? __builtin_amdgcn_rsqf(tl2) : 0.0f;

    const float d0 = pd0 * pri - td0 * tri;
    const float d1 = pd1 * pri - td1 * tri;
    const float d2 = pd2 * pri - td2 * tri;
    const float sq = m0*d0*d0 + m1*d1*d1 + m2*d2*d2;  // mask[:, :, :150] re-mask

    return ab + 0.1f * sq;
}

// Process one chunk of 8 consecutive triples starting at triple index chunk*8.
// All loads are issued into named registers FIRST (6 x dwordx4 + 2 x dwordx3
// per array), then 8 bone terms are computed from registers.
__device__ __forceinline__ float chunk8(const float* __restrict__ preds,
                                        const float* __restrict__ targets,
                                        unsigned chunk)
{
    const unsigned bt = chunk * (unsigned)TPT;        // base triple index
    const unsigned j0 = bt % 50u;                     // joint of triple 0
    const float* P = preds   + (size_t)bt * 3u;       // 16-B aligned (bt*12 B, bt%8==0... bt*12: 8*12=96)
    const float* T = targets + (size_t)bt * 3u;

    // successor triple (neighbor of triple 7 when j7 != 49, i.e. j0 != 42);
    // when j0 == 42 point at base (unused, keeps last chunk in-bounds)
    const int eoff = (j0 == 42u) ? 0 : TPT * 3;
    // frame-wrap target (joint 0 of the frame containing the j==49 triple);
    // only meaningful when j0 >= 42, else points at base (L1 hit, unused)
    const int woff = (j0 >= 42u) ? -(int)(3u * j0) : 0;

    // ---- load phase: everything into registers, no compute in between ----
    float p[27], t[27], pw[3], tw[3];
    const float4* P4 = reinterpret_cast<const float4*>(P);
    const float4* T4 = reinterpret_cast<const float4*>(T);
    #pragma unroll
    for (int i = 0; i < 6; ++i) {
        const float4 a = P4[i];
        p[4*i+0] = a.x; p[4*i+1] = a.y; p[4*i+2] = a.z; p[4*i+3] = a.w;
        const float4 b = T4[i];
        t[4*i+0] = b.x; t[4*i+1] = b.y; t[4*i+2] = b.z; t[4*i+3] = b.w;
    }
    p[24] = P[eoff+0]; p[25] = P[eoff+1]; p[26] = P[eoff+2];
    t[24] = T[eoff+0]; t[25] = T[eoff+1]; t[26] = T[eoff+2];
    pw[0] = P[woff+0]; pw[1] = P[woff+1]; pw[2] = P[woff+2];
    tw[0] = T[woff+0]; tw[1] = T[woff+1]; tw[2] = T[woff+2];

    // ---- compute phase: neighbor of triple k is triple k+1 (in-register),
    // except the one wrapping triple (j == 49) which uses the frame start.
    // Wrap condition is uniformly j0 == 49-k for k = 0..7 (k=7 -> 42).
    float acc = 0.0f;
    #pragma unroll
    for (int k = 0; k < TPT; ++k) {
        const bool w = (j0 == 49u - (unsigned)k);
        const int  n = 3 * (k + 1);                   // k==7 -> 24 (successor slot)
        const float q0 = w ? pw[0] : p[n+0];
        const float q1 = w ? pw[1] : p[n+1];
        const float q2 = w ? pw[2] : p[n+2];
        const float u0 = w ? tw[0] : t[n+0];
        const float u1 = w ? tw[1] : t[n+1];
        const float u2 = w ? tw[2] : t[n+2];
        acc += bone_term(p[3*k+0], p[3*k+1], p[3*k+2],
                         t[3*k+0], t[3*k+1], t[3*k+2],
                         q0, q1, q2, u0, u1, u2);
    }
    return acc;
}

__global__ __launch_bounds__(BLOCK, 4) void bone_loss_main(
    const float* __restrict__ preds,
    const float* __restrict__ targets,
    float* __restrict__ partials)
{
    const unsigned th = blockIdx.x * BLOCK + threadIdx.x;

    // two far-apart chunks per thread, processed as two sequential
    // load-then-compute phases (each phase has 16 clustered loads in flight)
    float acc = chunk8(preds, targets, th)
              + chunk8(preds, targets, th + CSTRIDE);

    // ---- block reduction ----
    #pragma unroll
    for (int off = 32; off > 0; off >>= 1)
        acc += __shfl_down(acc, off, 64);

    __shared__ float ws[4];
    const int wid = threadIdx.x >> 6;
    if ((threadIdx.x & 63) == 0) ws[wid] = acc;
    __syncthreads();
    if (threadIdx.x == 0)
        partials[blockIdx.x] = ws[0] + ws[1] + ws[2] + ws[3];
}

__global__ __launch_bounds__(256) void bone_loss_finish(
    const float* __restrict__ partials,
    float* __restrict__ out)
{
    float v = 0.0f;
    for (int i = threadIdx.x; i < NBLK; i += 256)
        v += partials[i];

    #pragma unroll
    for (int off = 32; off > 0; off >>= 1)
        v += __shfl_down(v, off, 64);

    __shared__ float ws[4];
    const int wid = threadIdx.x >> 6;
    if ((threadIdx.x & 63) == 0) ws[wid] = v;
    __syncthreads();
    if (threadIdx.x == 0)
        out[0] = (ws[0] + ws[1] + ws[2] + ws[3]) * SCALE;
}

extern "C" void kernel_launch(void* const* d_in, const int* in_sizes, int n_in,
                              void* d_out, int out_size, void* d_ws, size_t ws_size,
                              hipStream_t stream) {
    const float* preds   = (const float*)d_in[0];
    const float* targets = (const float*)d_in[1];
    float* out      = (float*)d_out;
    float* partials = (float*)d_ws;       // NBLK floats = 6.4 KB

    bone_loss_main<<<NBLK, BLOCK, 0, stream>>>(preds, targets, partials);
    bone_loss_finish<<<1, 256, 0, stream>>>(partials, out);
}